// Round 3
// baseline (198.693 us; speedup 1.0000x reference)
//
#include <hip/hip_runtime.h>
#include <math.h>

typedef unsigned short u16;
typedef unsigned int u32;
typedef short short8 __attribute__((ext_vector_type(8)));
typedef float f32x4 __attribute__((ext_vector_type(4)));
typedef float f4 __attribute__((ext_vector_type(4)));
typedef unsigned short u16x4 __attribute__((ext_vector_type(4)));
typedef unsigned int u32x2 __attribute__((ext_vector_type(2)));

// ---------- helpers ----------
__device__ __forceinline__ u16 f2bf(float f) {
  unsigned u = __builtin_bit_cast(unsigned, f);
  u += 0x7fffu + ((u >> 16) & 1u);
  return (u16)(u >> 16);
}

__device__ __forceinline__ u32 cvtpk_bf16(float a, float b) {
  u32 r;
  asm("v_cvt_pk_bf16_f32 %0, %1, %2" : "=v"(r) : "v"(a), "v"(b));
  return r;  // lo16 = bf16(a), hi16 = bf16(b)
}

__device__ __forceinline__ void gload16(const void* g, void* l) {
  __builtin_amdgcn_global_load_lds((const __attribute__((address_space(1))) void*)g,
                                   (__attribute__((address_space(3))) void*)l, 16, 0, 0);
}

// ---------- fp32 -> bf16 cast (x) ----------
__global__ __launch_bounds__(256) void convert_x_kernel(const float* __restrict__ in,
                                                        u16* __restrict__ out, int n4) {
  int i = blockIdx.x * 256 + threadIdx.x;
  int stride = gridDim.x * 256;
  for (; i < n4; i += stride) {
    f4 v = ((const f4*)in)[i];
    u16x4 o;
    o[0] = f2bf(v[0]); o[1] = f2bf(v[1]); o[2] = f2bf(v[2]); o[3] = f2bf(v[3]);
    ((u16x4*)out)[i] = o;
  }
}

// ---------- fp32 [R][C] -> bf16 [C][R] transpose; rows < qcols of output scaled ----------
__global__ __launch_bounds__(256) void transpose_w_kernel(const float* __restrict__ in,
                                                          u16* __restrict__ out, int R, int C,
                                                          int qcols, float qscale) {
  __shared__ float t[32][33];
  int j0 = blockIdx.x * 32, i0 = blockIdx.y * 32;
  int tx = threadIdx.x, ty = threadIdx.y;  // 32 x 8
#pragma unroll
  for (int k = 0; k < 4; ++k) t[ty + 8 * k][tx] = in[(size_t)(i0 + ty + 8 * k) * C + j0 + tx];
  __syncthreads();
#pragma unroll
  for (int k = 0; k < 4; ++k) {
    int orow = j0 + ty + 8 * k;
    float v = t[tx][ty + 8 * k];
    if (orow < qcols) v *= qscale;
    out[(size_t)orow * R + i0 + tx] = f2bf(v);
  }
}

// ---------- V transpose: qkv v-part [t][d] -> Vt[bh][d][t] (bf16) ----------
__global__ __launch_bounds__(256) void transV_kernel(const u16* __restrict__ qkv,
                                                     u16* __restrict__ Vt) {
  __shared__ u16 t[32][72];
  int t0 = blockIdx.x * 32;
  int bh = blockIdx.y, b = bh >> 4, h = bh & 15;
  int tid = threadIdx.x;
  int tx = tid & 63, ty = tid >> 6;  // 64 x 4
#pragma unroll
  for (int p = 0; p < 8; ++p) {
    int tt = ty + p * 4;
    t[tt][tx] = qkv[(size_t)(b * 2048 + t0 + tt) * 3072 + 2048 + h * 64 + tx];
  }
  __syncthreads();
  int t2 = tid & 31, d2 = tid >> 5;  // 32 t x 8 d
#pragma unroll
  for (int p = 0; p < 8; ++p) {
    int d = d2 + p * 8;
    Vt[(size_t)bh * 131072 + (size_t)d * 2048 + t0 + t2] = t[t2][d];
  }
}

// ---------- GEMM: C[m][n] = sum_k A[m][k] * Bt[n][k], bf16 in, fp32 acc ----------
template <int BF16_OUT>
__global__ __launch_bounds__(256) void gemm_kernel(const u16* __restrict__ A,
                                                   const u16* __restrict__ Bt,
                                                   void* __restrict__ Cv, int N, int K) {
  __shared__ __align__(16) u16 lA[128 * 64];
  __shared__ __align__(16) u16 lB[128 * 64];
  const int tid = threadIdx.x;
  const int w = tid >> 6, lane = tid & 63, lo = lane & 15, hi = lane >> 4;
  const int wm = w >> 1, wn = w & 1;
  const int m0 = blockIdx.y * 128, n0 = blockIdx.x * 128;
  f32x4 acc[4][4] = {};
  const int nkt = K >> 6;
  for (int kt = 0; kt < nkt; ++kt) {
    const int k0 = kt * 64;
#pragma unroll
    for (int c = 0; c < 4; ++c) {
      int flat = tid + c * 256;
      int r = flat >> 3, kc = flat & 7;
      int kcs = kc ^ (r & 7);
      gload16(A + (size_t)(m0 + r) * K + k0 + kcs * 8, (char*)lA + flat * 16);
      gload16(Bt + (size_t)(n0 + r) * K + k0 + kcs * 8, (char*)lB + flat * 16);
    }
    __syncthreads();
#pragma unroll
    for (int kk = 0; kk < 2; ++kk) {
      short8 af[4], bf[4];
#pragma unroll
      for (int mf = 0; mf < 4; ++mf) {
        int row = wm * 64 + mf * 16 + lo;
        int addr = (row * 128 + kk * 64 + hi * 16) ^ ((row & 7) << 4);
        af[mf] = *(const short8*)((const char*)lA + addr);
      }
#pragma unroll
      for (int nf = 0; nf < 4; ++nf) {
        int row = wn * 64 + nf * 16 + lo;
        int addr = (row * 128 + kk * 64 + hi * 16) ^ ((row & 7) << 4);
        bf[nf] = *(const short8*)((const char*)lB + addr);
      }
#pragma unroll
      for (int mf = 0; mf < 4; ++mf)
#pragma unroll
        for (int nf = 0; nf < 4; ++nf)
          acc[mf][nf] = __builtin_amdgcn_mfma_f32_16x16x32_bf16(af[mf], bf[nf], acc[mf][nf], 0, 0, 0);
    }
    __syncthreads();
  }
#pragma unroll
  for (int mf = 0; mf < 4; ++mf)
#pragma unroll
    for (int nf = 0; nf < 4; ++nf)
#pragma unroll
      for (int r = 0; r < 4; ++r) {
        int row = m0 + wm * 64 + mf * 16 + hi * 4 + r;
        int col = n0 + wn * 64 + nf * 16 + lo;
        float v = acc[mf][nf][r];
        if (BF16_OUT)
          ((u16*)Cv)[(size_t)row * N + col] = f2bf(v);
        else
          ((float*)Cv)[(size_t)row * N + col] = v;
      }
}

// ---------- flash attention ----------
// 4096 single-wave blocks. bx -> qt = 127 - bx/32 (heavy tiles first), bh = bx&31.
// Wave owns 16 q rows, KV tiles of 64. Swapped QK^T (q on lane&15).
// Q pre-scaled by rsqrt(L)*log2e (folded into W_attn^T), so softmax is exp2(st - m).
// T13 defer-max: skip rescale when max grows < 8 (log2 units) -> rescale ~once/block.
__global__ __launch_bounds__(64, 4) void attn_kernel(const u16* __restrict__ qkv,
                                                     const u16* __restrict__ Vt,
                                                     u16* __restrict__ yb) {
  __shared__ __align__(16) u16 pl[16][72];     // P tile [q][k], stride 144B
  __shared__ __align__(16) float rowstat[16];  // per-q fac / inv broadcast
  const int lane = threadIdx.x;
  const int lo = lane & 15, hi = lane >> 4;
  const int bx = blockIdx.x;
  const int qt = 127 - (bx >> 5);
  const int bh = bx & 31, b = bh >> 4, h = bh & 15;
  const int q0 = qt * 16;

  const u16* qbase = qkv + (size_t)b * 2048 * 3072 + h * 64 + hi * 8;
  short8 qf[2];
#pragma unroll
  for (int kk = 0; kk < 2; ++kk)
    qf[kk] = *(const short8*)(qbase + (size_t)(q0 + lo) * 3072 + kk * 32);

  float mrun = -INFINITY, lrun = 0.f;
  f32x4 yacc[4] = {};

  const int nt = (q0 >> 6) + 1;
  for (int it = 0; it < nt; ++it) {
    const int t0 = it * 64;
    short8 kf[4][2];
#pragma unroll
    for (int n = 0; n < 4; ++n)
#pragma unroll
      for (int kk = 0; kk < 2; ++kk)
        kf[n][kk] = *(const short8*)(qbase + (size_t)(t0 + n * 16 + lo) * 3072 + 1024 + kk * 32);
    f32x4 st[4] = {};  // st[n][r] = S^T[k = t0+n*16+4hi+r][q = q0+lo]  (pre-scaled)
#pragma unroll
    for (int kk = 0; kk < 2; ++kk)
#pragma unroll
      for (int n = 0; n < 4; ++n)
        st[n] = __builtin_amdgcn_mfma_f32_16x16x32_bf16(kf[n][kk], qf[kk], st[n], 0, 0, 0);

    float mx = -INFINITY;
    if (t0 + 63 > q0) {  // wave-uniform: this tile needs the causal mask
      const int q = q0 + lo;
#pragma unroll
      for (int n = 0; n < 4; ++n)
#pragma unroll
        for (int r = 0; r < 4; ++r) {
          const int k = t0 + n * 16 + hi * 4 + r;
          float v = (k <= q) ? st[n][r] : -INFINITY;
          st[n][r] = v;
          mx = fmaxf(mx, v);
        }
    } else {
#pragma unroll
      for (int n = 0; n < 4; ++n)
#pragma unroll
        for (int r = 0; r < 4; ++r) mx = fmaxf(mx, st[n][r]);
    }
    mx = fmaxf(mx, __shfl_xor(mx, 16));
    mx = fmaxf(mx, __shfl_xor(mx, 32));

    if (!__all(mx <= mrun + 8.f)) {  // rescale path (~once per block)
      float nm = fmaxf(mrun, mx);
      float fac = exp2f(mrun - nm);
      mrun = nm;
      lrun *= fac;
      if (hi == 0) rowstat[lo] = fac;
      __syncthreads();
      f32x4 fv = *(const f32x4*)&rowstat[hi * 4];
#pragma unroll
      for (int nf = 0; nf < 4; ++nf)
#pragma unroll
        for (int r = 0; r < 4; ++r) yacc[nf][r] *= fv[r];
    }

    float rs = 0.f;
#pragma unroll
    for (int n = 0; n < 4; ++n) {
      float p0 = exp2f(st[n][0] - mrun);
      float p1 = exp2f(st[n][1] - mrun);
      float p2 = exp2f(st[n][2] - mrun);
      float p3 = exp2f(st[n][3] - mrun);
      rs += (p0 + p1) + (p2 + p3);
      u32x2 w;
      w[0] = cvtpk_bf16(p0, p1);
      w[1] = cvtpk_bf16(p2, p3);
      *(u32x2*)&pl[lo][n * 16 + hi * 4] = w;
    }
    rs += __shfl_xor(rs, 16);
    rs += __shfl_xor(rs, 32);
    lrun += rs;
    __syncthreads();

#pragma unroll
    for (int kk2 = 0; kk2 < 2; ++kk2) {
      short8 pa = *(const short8*)&pl[lo][kk2 * 32 + hi * 8];
      short8 vf[4];
#pragma unroll
      for (int nf = 0; nf < 4; ++nf)
        vf[nf] = *(const short8*)(Vt + (size_t)bh * 131072 + (size_t)(nf * 16 + lo) * 2048 +
                                  t0 + kk2 * 32 + hi * 8);
#pragma unroll
      for (int nf = 0; nf < 4; ++nf)
        yacc[nf] = __builtin_amdgcn_mfma_f32_16x16x32_bf16(pa, vf[nf], yacc[nf], 0, 0, 0);
    }
  }

  if (hi == 0) rowstat[lo] = 1.f / lrun;
  __syncthreads();
  f32x4 iv = *(const f32x4*)&rowstat[hi * 4];
#pragma unroll
  for (int nf = 0; nf < 4; ++nf)
#pragma unroll
    for (int r = 0; r < 4; ++r)
      yb[(size_t)(b * 2048 + q0 + hi * 4 + r) * 1024 + h * 64 + nf * 16 + lo] =
          f2bf(yacc[nf][r] * iv[r]);
}

extern "C" void kernel_launch(void* const* d_in, const int* in_sizes, int n_in,
                              void* d_out, int out_size, void* d_ws, size_t ws_size,
                              hipStream_t stream) {
  const float* x = (const float*)d_in[0];    // [4096][1024]
  const float* Wa = (const float*)d_in[1];   // [1024][3072]
  const float* Wp = (const float*)d_in[2];   // [1024][1024]
  char* ws = (char*)d_ws;
  u16* xb   = (u16*)(ws);              // [4096][1024] bf16
  u16* Wat  = (u16*)(ws + 8388608);    // [3072][1024] bf16 (W_attn^T, Q rows pre-scaled)
  u16* Wpt  = (u16*)(ws + 14680064);   // [1024][1024] bf16 (W_proj^T)
  u16* qkvb = (u16*)(ws + 16777216);   // [4096][3072] bf16
  u16* Vt   = (u16*)(ws + 41943040);   // [32][64][2048] bf16
  u16* yb   = (u16*)(ws + 50331648);   // [4096][1024] bf16

  const float CS = 0.03125f * 1.44269504088896f;  // rsqrt(1024) * log2(e)
  convert_x_kernel<<<1024, 256, 0, stream>>>(x, xb, 4194304 / 4);
  transpose_w_kernel<<<dim3(96, 32), dim3(32, 8), 0, stream>>>(Wa, Wat, 1024, 3072, 1024, CS);
  transpose_w_kernel<<<dim3(32, 32), dim3(32, 8), 0, stream>>>(Wp, Wpt, 1024, 1024, 0, 1.f);
  gemm_kernel<1><<<dim3(24, 32), 256, 0, stream>>>(xb, Wat, (void*)qkvb, 3072, 1024);
  transV_kernel<<<dim3(64, 32), 256, 0, stream>>>(qkvb, Vt);
  attn_kernel<<<4096, 64, 0, stream>>>(qkvb, Vt, yb);
  gemm_kernel<0><<<dim3(8, 32), 256, 0, stream>>>(yb, Wpt, d_out, 1024, 1024);
}

// Round 4
// 151.512 us; speedup vs baseline: 1.3114x; 1.3114x over previous
//
#include <hip/hip_runtime.h>
#include <math.h>

typedef unsigned short u16;
typedef unsigned int u32;
typedef short short8 __attribute__((ext_vector_type(8)));
typedef float f32x4 __attribute__((ext_vector_type(4)));
typedef float f4 __attribute__((ext_vector_type(4)));
typedef unsigned short u16x4 __attribute__((ext_vector_type(4)));
typedef unsigned int u32x2 __attribute__((ext_vector_type(2)));

// ---------- helpers ----------
__device__ __forceinline__ u16 f2bf(float f) {
  unsigned u = __builtin_bit_cast(unsigned, f);
  u += 0x7fffu + ((u >> 16) & 1u);
  return (u16)(u >> 16);
}

__device__ __forceinline__ float bf2f(u16 v) {
  return __builtin_bit_cast(float, (u32)v << 16);
}

__device__ __forceinline__ u32 cvtpk_bf16(float a, float b) {
  u32 r;
  asm("v_cvt_pk_bf16_f32 %0, %1, %2" : "=v"(r) : "v"(a), "v"(b));
  return r;  // lo16 = bf16(a), hi16 = bf16(b)
}

__device__ __forceinline__ void gload16(const void* g, void* l) {
  __builtin_amdgcn_global_load_lds((const __attribute__((address_space(1))) void*)g,
                                   (__attribute__((address_space(3))) void*)l, 16, 0, 0);
}

// ---------- fp32 -> bf16 cast (x) ----------
__global__ __launch_bounds__(256) void convert_x_kernel(const float* __restrict__ in,
                                                        u16* __restrict__ out, int n4) {
  int i = blockIdx.x * 256 + threadIdx.x;
  int stride = gridDim.x * 256;
  for (; i < n4; i += stride) {
    f4 v = ((const f4*)in)[i];
    u16x4 o;
    o[0] = f2bf(v[0]); o[1] = f2bf(v[1]); o[2] = f2bf(v[2]); o[3] = f2bf(v[3]);
    ((u16x4*)out)[i] = o;
  }
}

// ---------- fp32 [R][C] -> bf16 [C][R] transpose; output rows < qcols scaled ----------
__global__ __launch_bounds__(256) void transpose_w_kernel(const float* __restrict__ in,
                                                          u16* __restrict__ out, int R, int C,
                                                          int qcols, float qscale) {
  __shared__ float t[32][33];
  int j0 = blockIdx.x * 32, i0 = blockIdx.y * 32;
  int tx = threadIdx.x, ty = threadIdx.y;  // 32 x 8
#pragma unroll
  for (int k = 0; k < 4; ++k) t[ty + 8 * k][tx] = in[(size_t)(i0 + ty + 8 * k) * C + j0 + tx];
  __syncthreads();
#pragma unroll
  for (int k = 0; k < 4; ++k) {
    int orow = j0 + ty + 8 * k;
    float v = t[tx][ty + 8 * k];
    if (orow < qcols) v *= qscale;
    out[(size_t)orow * R + i0 + tx] = f2bf(v);
  }
}

// ---------- V transpose: qkv v-part [t][d] -> Vt[bh][d][t] (bf16) ----------
__global__ __launch_bounds__(256) void transV_kernel(const u16* __restrict__ qkv,
                                                     u16* __restrict__ Vt) {
  __shared__ u16 t[32][72];
  int t0 = blockIdx.x * 32;
  int bh = blockIdx.y, b = bh >> 4, h = bh & 15;
  int tid = threadIdx.x;
  int tx = tid & 63, ty = tid >> 6;  // 64 x 4
#pragma unroll
  for (int p = 0; p < 8; ++p) {
    int tt = ty + p * 4;
    t[tt][tx] = qkv[(size_t)(b * 2048 + t0 + tt) * 3072 + 2048 + h * 64 + tx];
  }
  __syncthreads();
  int t2 = tid & 31, d2 = tid >> 5;  // 32 t x 8 d
#pragma unroll
  for (int p = 0; p < 8; ++p) {
    int d = d2 + p * 8;
    Vt[(size_t)bh * 131072 + (size_t)d * 2048 + t0 + t2] = t[t2][d];
  }
}

// ---------- GEMM: C[m][n] = sum_k A[m][k] * Bt[n][k], bf16 in, fp32 acc ----------
template <int BF16_OUT>
__global__ __launch_bounds__(256) void gemm_kernel(const u16* __restrict__ A,
                                                   const u16* __restrict__ Bt,
                                                   void* __restrict__ Cv, int N, int K) {
  __shared__ __align__(16) u16 lA[128 * 64];
  __shared__ __align__(16) u16 lB[128 * 64];
  const int tid = threadIdx.x;
  const int w = tid >> 6, lane = tid & 63, lo = lane & 15, hi = lane >> 4;
  const int wm = w >> 1, wn = w & 1;
  const int m0 = blockIdx.y * 128, n0 = blockIdx.x * 128;
  f32x4 acc[4][4] = {};
  const int nkt = K >> 6;
  for (int kt = 0; kt < nkt; ++kt) {
    const int k0 = kt * 64;
#pragma unroll
    for (int c = 0; c < 4; ++c) {
      int flat = tid + c * 256;
      int r = flat >> 3, kc = flat & 7;
      int kcs = kc ^ (r & 7);
      gload16(A + (size_t)(m0 + r) * K + k0 + kcs * 8, (char*)lA + flat * 16);
      gload16(Bt + (size_t)(n0 + r) * K + k0 + kcs * 8, (char*)lB + flat * 16);
    }
    __syncthreads();
#pragma unroll
    for (int kk = 0; kk < 2; ++kk) {
      short8 af[4], bf[4];
#pragma unroll
      for (int mf = 0; mf < 4; ++mf) {
        int row = wm * 64 + mf * 16 + lo;
        int addr = (row * 128 + kk * 64 + hi * 16) ^ ((row & 7) << 4);
        af[mf] = *(const short8*)((const char*)lA + addr);
      }
#pragma unroll
      for (int nf = 0; nf < 4; ++nf) {
        int row = wn * 64 + nf * 16 + lo;
        int addr = (row * 128 + kk * 64 + hi * 16) ^ ((row & 7) << 4);
        bf[nf] = *(const short8*)((const char*)lB + addr);
      }
#pragma unroll
      for (int mf = 0; mf < 4; ++mf)
#pragma unroll
        for (int nf = 0; nf < 4; ++nf)
          acc[mf][nf] = __builtin_amdgcn_mfma_f32_16x16x32_bf16(af[mf], bf[nf], acc[mf][nf], 0, 0, 0);
    }
    __syncthreads();
  }
#pragma unroll
  for (int mf = 0; mf < 4; ++mf)
#pragma unroll
    for (int nf = 0; nf < 4; ++nf)
#pragma unroll
      for (int r = 0; r < 4; ++r) {
        int row = m0 + wm * 64 + mf * 16 + hi * 4 + r;
        int col = n0 + wn * 64 + nf * 16 + lo;
        float v = acc[mf][nf][r];
        if (BF16_OUT)
          ((u16*)Cv)[(size_t)row * N + col] = f2bf(v);
        else
          ((float*)Cv)[(size_t)row * N + col] = v;
      }
}

// ---------- flash attention, 4-way KV-split within block ----------
// 2048 blocks x 4 waves. bx -> qt = 63 - bx/32 (heavy first), bh = bx & 31.
// Block owns 32 q rows; wave w processes KV tiles it = w, w+4, ... with private
// online-softmax state (m, l, O). End: one barrier, combine 4 partials in LDS.
// Swapped QK^T (q on lane&15); Q pre-scaled by rsqrt(L)*log2e; T13 defer-max.
__global__ __launch_bounds__(256) void attn_kernel(const u16* __restrict__ qkv,
                                                   const u16* __restrict__ Vt,
                                                   u16* __restrict__ yb) {
  __shared__ __align__(16) u16 pl[4][32][72];  // per-wave P tile; reused for O partial (bf16)
  __shared__ float mst[4][32], lst[4][32], rowstat[4][32];
  const int tid = threadIdx.x, w = tid >> 6, lane = tid & 63;
  const int lo = lane & 15, hi = lane >> 4;
  const int bx = blockIdx.x;
  const int qt = 63 - (bx >> 5);
  const int bh = bx & 31, b = bh >> 4, h = bh & 15;
  const int q0 = qt * 32;

  const u16* qbase = qkv + (size_t)b * 2048 * 3072 + h * 64 + hi * 8;
  short8 qf[2][2];
#pragma unroll
  for (int m = 0; m < 2; ++m)
#pragma unroll
    for (int kk = 0; kk < 2; ++kk)
      qf[m][kk] = *(const short8*)(qbase + (size_t)(q0 + m * 16 + lo) * 3072 + kk * 32);

  float mrun[2] = {-INFINITY, -INFINITY}, lrun[2] = {0.f, 0.f};
  f32x4 yacc[2][4] = {};

  const int nt = (q0 >> 6) + 1;
  for (int it = w; it < nt; it += 4) {
    const int t0 = it * 64;
    short8 kf[4][2];
#pragma unroll
    for (int n = 0; n < 4; ++n)
#pragma unroll
      for (int kk = 0; kk < 2; ++kk)
        kf[n][kk] = *(const short8*)(qbase + (size_t)(t0 + n * 16 + lo) * 3072 + 1024 + kk * 32);
    f32x4 st[4][2] = {};  // st[n][m][r] = S^T[k=t0+n*16+4hi+r][q=q0+m*16+lo] (pre-scaled)
#pragma unroll
    for (int kk = 0; kk < 2; ++kk)
#pragma unroll
      for (int n = 0; n < 4; ++n)
#pragma unroll
        for (int m = 0; m < 2; ++m)
          st[n][m] = __builtin_amdgcn_mfma_f32_16x16x32_bf16(kf[n][kk], qf[m][kk], st[n][m], 0, 0, 0);

    float mx[2] = {-INFINITY, -INFINITY};
    if (t0 + 63 > q0) {  // wave-uniform: tile straddles the diagonal
#pragma unroll
      for (int m = 0; m < 2; ++m) {
        const int q = q0 + m * 16 + lo;
#pragma unroll
        for (int n = 0; n < 4; ++n)
#pragma unroll
          for (int r = 0; r < 4; ++r) {
            const int k = t0 + n * 16 + hi * 4 + r;
            float v = (k <= q) ? st[n][m][r] : -INFINITY;
            st[n][m][r] = v;
            mx[m] = fmaxf(mx[m], v);
          }
      }
    } else {
#pragma unroll
      for (int m = 0; m < 2; ++m)
#pragma unroll
        for (int n = 0; n < 4; ++n)
#pragma unroll
          for (int r = 0; r < 4; ++r) mx[m] = fmaxf(mx[m], st[n][m][r]);
    }
#pragma unroll
    for (int m = 0; m < 2; ++m) {
      mx[m] = fmaxf(mx[m], __shfl_xor(mx[m], 16));
      mx[m] = fmaxf(mx[m], __shfl_xor(mx[m], 32));
    }

    if (!__all(mx[0] <= mrun[0] + 8.f && mx[1] <= mrun[1] + 8.f)) {  // rare rescale
      float fac[2];
#pragma unroll
      for (int m = 0; m < 2; ++m) {
        float nm = fmaxf(mrun[m], mx[m]);
        fac[m] = exp2f(mrun[m] - nm);
        mrun[m] = nm;
        lrun[m] *= fac[m];
      }
      if (hi == 0) { rowstat[w][lo] = fac[0]; rowstat[w][16 + lo] = fac[1]; }
      asm volatile("s_waitcnt lgkmcnt(0)" ::: "memory");
#pragma unroll
      for (int mf = 0; mf < 2; ++mf) {
        f32x4 fv = *(const f32x4*)&rowstat[w][mf * 16 + hi * 4];
#pragma unroll
        for (int nf = 0; nf < 4; ++nf)
#pragma unroll
          for (int r = 0; r < 4; ++r) yacc[mf][nf][r] *= fv[r];
      }
    }

#pragma unroll
    for (int m = 0; m < 2; ++m) {
      float rs = 0.f;
#pragma unroll
      for (int n = 0; n < 4; ++n) {
        float p0 = exp2f(st[n][m][0] - mrun[m]);
        float p1 = exp2f(st[n][m][1] - mrun[m]);
        float p2 = exp2f(st[n][m][2] - mrun[m]);
        float p3 = exp2f(st[n][m][3] - mrun[m]);
        rs += (p0 + p1) + (p2 + p3);
        u32x2 pw;
        pw[0] = cvtpk_bf16(p0, p1);
        pw[1] = cvtpk_bf16(p2, p3);
        *(u32x2*)&pl[w][m * 16 + lo][n * 16 + hi * 4] = pw;
      }
      rs += __shfl_xor(rs, 16);
      rs += __shfl_xor(rs, 32);
      lrun[m] += rs;
    }
    asm volatile("s_waitcnt lgkmcnt(0)" ::: "memory");

#pragma unroll
    for (int kk2 = 0; kk2 < 2; ++kk2) {
      short8 pa[2], vf[4];
#pragma unroll
      for (int mf = 0; mf < 2; ++mf)
        pa[mf] = *(const short8*)&pl[w][mf * 16 + lo][kk2 * 32 + hi * 8];
#pragma unroll
      for (int nf = 0; nf < 4; ++nf)
        vf[nf] = *(const short8*)(Vt + (size_t)bh * 131072 + (size_t)(nf * 16 + lo) * 2048 +
                                  t0 + kk2 * 32 + hi * 8);
#pragma unroll
      for (int mf = 0; mf < 2; ++mf)
#pragma unroll
        for (int nf = 0; nf < 4; ++nf)
          yacc[mf][nf] = __builtin_amdgcn_mfma_f32_16x16x32_bf16(pa[mf], vf[nf], yacc[mf][nf], 0, 0, 0);
    }
  }

  // publish partials: stats + O tile (bf16, reusing pl[w])
  if (hi == 0) {
#pragma unroll
    for (int m = 0; m < 2; ++m) { mst[w][m * 16 + lo] = mrun[m]; lst[w][m * 16 + lo] = lrun[m]; }
  }
#pragma unroll
  for (int mf = 0; mf < 2; ++mf)
#pragma unroll
    for (int nf = 0; nf < 4; ++nf)
#pragma unroll
      for (int r = 0; r < 4; ++r)
        pl[w][mf * 16 + hi * 4 + r][nf * 16 + lo] = f2bf(yacc[mf][nf][r]);
  __syncthreads();

  // combine: wave w handles q rows [w*8, w*8+8); lane covers 8 d's
  {
    const int q = w * 8 + (lane >> 3), d0 = (lane & 7) * 8;
    float M = fmaxf(fmaxf(mst[0][q], mst[1][q]), fmaxf(mst[2][q], mst[3][q]));
    float L = 0.f;
    float o[8] = {};
#pragma unroll
    for (int ww = 0; ww < 4; ++ww) {
      float sc = exp2f(mst[ww][q] - M);
      L += sc * lst[ww][q];
      short8 ov = *(const short8*)&pl[ww][q][d0];
#pragma unroll
      for (int j = 0; j < 8; ++j) o[j] += sc * bf2f((u16)ov[j]);
    }
    float invL = 1.f / L;
    short8 ob;
#pragma unroll
    for (int j = 0; j < 8; ++j) ob[j] = (short)f2bf(o[j] * invL);
    *(short8*)&yb[(size_t)(b * 2048 + q0 + q) * 1024 + h * 64 + d0] = ob;
  }
}

extern "C" void kernel_launch(void* const* d_in, const int* in_sizes, int n_in,
                              void* d_out, int out_size, void* d_ws, size_t ws_size,
                              hipStream_t stream) {
  const float* x = (const float*)d_in[0];    // [4096][1024]
  const float* Wa = (const float*)d_in[1];   // [1024][3072]
  const float* Wp = (const float*)d_in[2];   // [1024][1024]
  char* ws = (char*)d_ws;
  u16* xb   = (u16*)(ws);              // [4096][1024] bf16
  u16* Wat  = (u16*)(ws + 8388608);    // [3072][1024] bf16 (W_attn^T, Q rows pre-scaled)
  u16* Wpt  = (u16*)(ws + 14680064);   // [1024][1024] bf16 (W_proj^T)
  u16* qkvb = (u16*)(ws + 16777216);   // [4096][3072] bf16
  u16* Vt   = (u16*)(ws + 41943040);   // [32][64][2048] bf16
  u16* yb   = (u16*)(ws + 50331648);   // [4096][1024] bf16

  const float CS = 0.03125f * 1.44269504088896f;  // rsqrt(1024) * log2(e)
  convert_x_kernel<<<1024, 256, 0, stream>>>(x, xb, 4194304 / 4);
  transpose_w_kernel<<<dim3(96, 32), dim3(32, 8), 0, stream>>>(Wa, Wat, 1024, 3072, 1024, CS);
  transpose_w_kernel<<<dim3(32, 32), dim3(32, 8), 0, stream>>>(Wp, Wpt, 1024, 1024, 0, 1.f);
  gemm_kernel<1><<<dim3(24, 32), 256, 0, stream>>>(xb, Wat, (void*)qkvb, 3072, 1024);
  transV_kernel<<<dim3(64, 32), 256, 0, stream>>>(qkvb, Vt);
  attn_kernel<<<2048, 256, 0, stream>>>(qkvb, Vt, yb);
  gemm_kernel<0><<<dim3(8, 32), 256, 0, stream>>>(yb, Wpt, d_out, 1024, 1024);
}

// Round 5
// 143.517 us; speedup vs baseline: 1.3845x; 1.0557x over previous
//
#include <hip/hip_runtime.h>
#include <math.h>

typedef unsigned short u16;
typedef unsigned int u32;
typedef short short8 __attribute__((ext_vector_type(8)));
typedef float f32x4 __attribute__((ext_vector_type(4)));
typedef float f4 __attribute__((ext_vector_type(4)));
typedef unsigned short u16x4 __attribute__((ext_vector_type(4)));
typedef unsigned int u32x2 __attribute__((ext_vector_type(2)));

// ---------- helpers ----------
__device__ __forceinline__ u16 f2bf(float f) {
  unsigned u = __builtin_bit_cast(unsigned, f);
  u += 0x7fffu + ((u >> 16) & 1u);
  return (u16)(u >> 16);
}

__device__ __forceinline__ float bf2f(u16 v) {
  return __builtin_bit_cast(float, (u32)v << 16);
}

__device__ __forceinline__ u32 cvtpk_bf16(float a, float b) {
  u32 r;
  asm("v_cvt_pk_bf16_f32 %0, %1, %2" : "=v"(r) : "v"(a), "v"(b));
  return r;  // lo16 = bf16(a), hi16 = bf16(b)
}

__device__ __forceinline__ void gload16(const void* g, void* l) {
  __builtin_amdgcn_global_load_lds((const __attribute__((address_space(1))) void*)g,
                                   (__attribute__((address_space(3))) void*)l, 16, 0, 0);
}

// ---------- merged prologue: convert x + transpose both weights ----------
// blocks [0,1024): x cast; [1024,4096): W_attn^T (Q rows scaled); [4096,5120): W_proj^T
__global__ __launch_bounds__(256) void prep_kernel(const float* __restrict__ x,
                                                   u16* __restrict__ xb,
                                                   const float* __restrict__ Wa,
                                                   u16* __restrict__ Wat,
                                                   const float* __restrict__ Wp,
                                                   u16* __restrict__ Wpt, float qscale) {
  __shared__ float t[32][33];
  const int bx = blockIdx.x, tid = threadIdx.x;
  if (bx < 1024) {
    const int n4 = 4194304 / 4;
    for (int i = bx * 256 + tid; i < n4; i += 1024 * 256) {
      f4 v = ((const f4*)x)[i];
      u16x4 o;
      o[0] = f2bf(v[0]); o[1] = f2bf(v[1]); o[2] = f2bf(v[2]); o[3] = f2bf(v[3]);
      ((u16x4*)xb)[i] = o;
    }
    return;
  }
  const float* in;
  u16* out;
  int R, C, j0, i0, qcols;
  if (bx < 4096) {
    int bid = bx - 1024;                       // 96 x 32 tiles
    in = Wa; out = Wat; R = 1024; C = 3072; qcols = 1024;
    j0 = (bid % 96) * 32; i0 = (bid / 96) * 32;
  } else {
    int bid = bx - 4096;                       // 32 x 32 tiles
    in = Wp; out = Wpt; R = 1024; C = 1024; qcols = 0;
    j0 = (bid % 32) * 32; i0 = (bid / 32) * 32;
  }
  const int tx = tid & 31, ty = tid >> 5;  // 32 x 8
#pragma unroll
  for (int k = 0; k < 4; ++k) t[ty + 8 * k][tx] = in[(size_t)(i0 + ty + 8 * k) * C + j0 + tx];
  __syncthreads();
#pragma unroll
  for (int k = 0; k < 4; ++k) {
    int orow = j0 + ty + 8 * k;
    float v = t[tx][ty + 8 * k];
    if (orow < qcols) v *= qscale;
    out[(size_t)orow * R + i0 + tx] = f2bf(v);
  }
}

// ---------- V transpose: qkv v-part [t][d] -> Vt[bh][d][t] (bf16) ----------
__global__ __launch_bounds__(256) void transV_kernel(const u16* __restrict__ qkv,
                                                     u16* __restrict__ Vt) {
  __shared__ u16 t[32][72];
  int t0 = blockIdx.x * 32;
  int bh = blockIdx.y, b = bh >> 4, h = bh & 15;
  int tid = threadIdx.x;
  int tx = tid & 63, ty = tid >> 6;  // 64 x 4
#pragma unroll
  for (int p = 0; p < 8; ++p) {
    int tt = ty + p * 4;
    t[tt][tx] = qkv[(size_t)(b * 2048 + t0 + tt) * 3072 + 2048 + h * 64 + tx];
  }
  __syncthreads();
  int t2 = tid & 31, d2 = tid >> 5;  // 32 t x 8 d
#pragma unroll
  for (int p = 0; p < 8; ++p) {
    int d = d2 + p * 8;
    Vt[(size_t)bh * 131072 + (size_t)d * 2048 + t0 + t2] = t[t2][d];
  }
}

// ---------- GEMM: C[m][n] = sum_k A[m][k] * Bt[n][k], bf16 in, fp32 acc ----------
template <int BF16_OUT>
__global__ __launch_bounds__(256) void gemm_kernel(const u16* __restrict__ A,
                                                   const u16* __restrict__ Bt,
                                                   void* __restrict__ Cv, int N, int K) {
  __shared__ __align__(16) u16 lA[128 * 64];
  __shared__ __align__(16) u16 lB[128 * 64];
  const int tid = threadIdx.x;
  const int w = tid >> 6, lane = tid & 63, lo = lane & 15, hi = lane >> 4;
  const int wm = w >> 1, wn = w & 1;
  const int m0 = blockIdx.y * 128, n0 = blockIdx.x * 128;
  f32x4 acc[4][4] = {};
  const int nkt = K >> 6;
  for (int kt = 0; kt < nkt; ++kt) {
    const int k0 = kt * 64;
#pragma unroll
    for (int c = 0; c < 4; ++c) {
      int flat = tid + c * 256;
      int r = flat >> 3, kc = flat & 7;
      int kcs = kc ^ (r & 7);
      gload16(A + (size_t)(m0 + r) * K + k0 + kcs * 8, (char*)lA + flat * 16);
      gload16(Bt + (size_t)(n0 + r) * K + k0 + kcs * 8, (char*)lB + flat * 16);
    }
    __syncthreads();
#pragma unroll
    for (int kk = 0; kk < 2; ++kk) {
      short8 af[4], bf[4];
#pragma unroll
      for (int mf = 0; mf < 4; ++mf) {
        int row = wm * 64 + mf * 16 + lo;
        int addr = (row * 128 + kk * 64 + hi * 16) ^ ((row & 7) << 4);
        af[mf] = *(const short8*)((const char*)lA + addr);
      }
#pragma unroll
      for (int nf = 0; nf < 4; ++nf) {
        int row = wn * 64 + nf * 16 + lo;
        int addr = (row * 128 + kk * 64 + hi * 16) ^ ((row & 7) << 4);
        bf[nf] = *(const short8*)((const char*)lB + addr);
      }
#pragma unroll
      for (int mf = 0; mf < 4; ++mf)
#pragma unroll
        for (int nf = 0; nf < 4; ++nf)
          acc[mf][nf] = __builtin_amdgcn_mfma_f32_16x16x32_bf16(af[mf], bf[nf], acc[mf][nf], 0, 0, 0);
    }
    __syncthreads();
  }
#pragma unroll
  for (int mf = 0; mf < 4; ++mf)
#pragma unroll
    for (int nf = 0; nf < 4; ++nf)
#pragma unroll
      for (int r = 0; r < 4; ++r) {
        int row = m0 + wm * 64 + mf * 16 + hi * 4 + r;
        int col = n0 + wn * 64 + nf * 16 + lo;
        float v = acc[mf][nf][r];
        if (BF16_OUT)
          ((u16*)Cv)[(size_t)row * N + col] = f2bf(v);
        else
          ((float*)Cv)[(size_t)row * N + col] = v;
      }
}

// ---------- flash attention, 4-way KV-split within block ----------
// 2048 blocks x 4 waves. bx -> qt = 63 - bx/32 (heavy first), bh = bx & 31.
// Block owns 32 q rows; wave w processes KV tiles it = w, w+4, ... with private
// online-softmax state. V loads issued EARLY (before softmax) so global latency
// hides under the VALU phase; s_setprio(1) wraps MFMA clusters (T5).
__global__ __launch_bounds__(256) void attn_kernel(const u16* __restrict__ qkv,
                                                   const u16* __restrict__ Vt,
                                                   u16* __restrict__ yb) {
  __shared__ __align__(16) u16 pl[4][32][72];  // per-wave P tile; reused for O partial (bf16)
  __shared__ float mst[4][32], lst[4][32], rowstat[4][32];
  const int tid = threadIdx.x, w = tid >> 6, lane = tid & 63;
  const int lo = lane & 15, hi = lane >> 4;
  const int bx = blockIdx.x;
  const int qt = 63 - (bx >> 5);
  const int bh = bx & 31, b = bh >> 4, h = bh & 15;
  const int q0 = qt * 32;

  const u16* qbase = qkv + (size_t)b * 2048 * 3072 + h * 64 + hi * 8;
  const u16* vbase = Vt + (size_t)bh * 131072 + (size_t)lo * 2048 + hi * 8;
  short8 qf[2][2];
#pragma unroll
  for (int m = 0; m < 2; ++m)
#pragma unroll
    for (int kk = 0; kk < 2; ++kk)
      qf[m][kk] = *(const short8*)(qbase + (size_t)(q0 + m * 16 + lo) * 3072 + kk * 32);

  float mrun[2] = {-INFINITY, -INFINITY}, lrun[2] = {0.f, 0.f};
  f32x4 yacc[2][4] = {};

  const int nt = (q0 >> 6) + 1;
  for (int it = w; it < nt; it += 4) {
    const int t0 = it * 64;
    short8 kf[4][2];
#pragma unroll
    for (int n = 0; n < 4; ++n)
#pragma unroll
      for (int kk = 0; kk < 2; ++kk)
        kf[n][kk] = *(const short8*)(qbase + (size_t)(t0 + n * 16 + lo) * 3072 + 1024 + kk * 32);
    f32x4 st[4][2] = {};  // st[n][m][r] = S^T[k=t0+n*16+4hi+r][q=q0+m*16+lo] (pre-scaled)
    __builtin_amdgcn_s_setprio(1);
#pragma unroll
    for (int kk = 0; kk < 2; ++kk)
#pragma unroll
      for (int n = 0; n < 4; ++n)
#pragma unroll
        for (int m = 0; m < 2; ++m)
          st[n][m] = __builtin_amdgcn_mfma_f32_16x16x32_bf16(kf[n][kk], qf[m][kk], st[n][m], 0, 0, 0);
    __builtin_amdgcn_s_setprio(0);

    // V kk2=0 fragments: issue NOW so latency hides under softmax VALU
    short8 vf0[4];
#pragma unroll
    for (int nf = 0; nf < 4; ++nf)
      vf0[nf] = *(const short8*)(vbase + (size_t)(nf * 16) * 2048 + t0);

    float mx[2] = {-INFINITY, -INFINITY};
    if (t0 + 63 > q0) {  // wave-uniform: tile straddles the diagonal
#pragma unroll
      for (int m = 0; m < 2; ++m) {
        const int q = q0 + m * 16 + lo;
#pragma unroll
        for (int n = 0; n < 4; ++n)
#pragma unroll
          for (int r = 0; r < 4; ++r) {
            const int k = t0 + n * 16 + hi * 4 + r;
            float v = (k <= q) ? st[n][m][r] : -INFINITY;
            st[n][m][r] = v;
            mx[m] = fmaxf(mx[m], v);
          }
      }
    } else {
#pragma unroll
      for (int m = 0; m < 2; ++m)
#pragma unroll
        for (int n = 0; n < 4; ++n)
#pragma unroll
          for (int r = 0; r < 4; ++r) mx[m] = fmaxf(mx[m], st[n][m][r]);
    }
#pragma unroll
    for (int m = 0; m < 2; ++m) {
      mx[m] = fmaxf(mx[m], __shfl_xor(mx[m], 16));
      mx[m] = fmaxf(mx[m], __shfl_xor(mx[m], 32));
    }

    if (!__all(mx[0] <= mrun[0] + 8.f && mx[1] <= mrun[1] + 8.f)) {  // rare rescale
      float fac[2];
#pragma unroll
      for (int m = 0; m < 2; ++m) {
        float nm = fmaxf(mrun[m], mx[m]);
        fac[m] = exp2f(mrun[m] - nm);
        mrun[m] = nm;
        lrun[m] *= fac[m];
      }
      if (hi == 0) { rowstat[w][lo] = fac[0]; rowstat[w][16 + lo] = fac[1]; }
      asm volatile("s_waitcnt lgkmcnt(0)" ::: "memory");
#pragma unroll
      for (int mf = 0; mf < 2; ++mf) {
        f32x4 fv = *(const f32x4*)&rowstat[w][mf * 16 + hi * 4];
#pragma unroll
        for (int nf = 0; nf < 4; ++nf)
#pragma unroll
          for (int r = 0; r < 4; ++r) yacc[mf][nf][r] *= fv[r];
      }
    }

#pragma unroll
    for (int m = 0; m < 2; ++m) {
      float rs = 0.f;
#pragma unroll
      for (int n = 0; n < 4; ++n) {
        float p0 = exp2f(st[n][m][0] - mrun[m]);
        float p1 = exp2f(st[n][m][1] - mrun[m]);
        float p2 = exp2f(st[n][m][2] - mrun[m]);
        float p3 = exp2f(st[n][m][3] - mrun[m]);
        rs += (p0 + p1) + (p2 + p3);
        u32x2 pw;
        pw[0] = cvtpk_bf16(p0, p1);
        pw[1] = cvtpk_bf16(p2, p3);
        *(u32x2*)&pl[w][m * 16 + lo][n * 16 + hi * 4] = pw;
      }
      rs += __shfl_xor(rs, 16);
      rs += __shfl_xor(rs, 32);
      lrun[m] += rs;
    }

    // V kk2=1 fragments: issue before the LDS fence (already in flight across it)
    short8 vf1[4];
#pragma unroll
    for (int nf = 0; nf < 4; ++nf)
      vf1[nf] = *(const short8*)(vbase + (size_t)(nf * 16) * 2048 + t0 + 32);

    asm volatile("s_waitcnt lgkmcnt(0)" ::: "memory");

    short8 pa0[2], pa1[2];
#pragma unroll
    for (int mf = 0; mf < 2; ++mf) {
      pa0[mf] = *(const short8*)&pl[w][mf * 16 + lo][hi * 8];
      pa1[mf] = *(const short8*)&pl[w][mf * 16 + lo][32 + hi * 8];
    }
    __builtin_amdgcn_s_setprio(1);
#pragma unroll
    for (int mf = 0; mf < 2; ++mf)
#pragma unroll
      for (int nf = 0; nf < 4; ++nf)
        yacc[mf][nf] = __builtin_amdgcn_mfma_f32_16x16x32_bf16(pa0[mf], vf0[nf], yacc[mf][nf], 0, 0, 0);
#pragma unroll
    for (int mf = 0; mf < 2; ++mf)
#pragma unroll
      for (int nf = 0; nf < 4; ++nf)
        yacc[mf][nf] = __builtin_amdgcn_mfma_f32_16x16x32_bf16(pa1[mf], vf1[nf], yacc[mf][nf], 0, 0, 0);
    __builtin_amdgcn_s_setprio(0);
  }

  // publish partials: stats + O tile (bf16, reusing pl[w])
  if (hi == 0) {
#pragma unroll
    for (int m = 0; m < 2; ++m) { mst[w][m * 16 + lo] = mrun[m]; lst[w][m * 16 + lo] = lrun[m]; }
  }
#pragma unroll
  for (int mf = 0; mf < 2; ++mf)
#pragma unroll
    for (int nf = 0; nf < 4; ++nf)
#pragma unroll
      for (int r = 0; r < 4; ++r)
        pl[w][mf * 16 + hi * 4 + r][nf * 16 + lo] = f2bf(yacc[mf][nf][r]);
  __syncthreads();

  // combine: wave w handles q rows [w*8, w*8+8); lane covers 8 d's
  {
    const int q = w * 8 + (lane >> 3), d0 = (lane & 7) * 8;
    float M = fmaxf(fmaxf(mst[0][q], mst[1][q]), fmaxf(mst[2][q], mst[3][q]));
    float L = 0.f;
    float o[8] = {};
#pragma unroll
    for (int ww = 0; ww < 4; ++ww) {
      float sc = exp2f(mst[ww][q] - M);
      L += sc * lst[ww][q];
      short8 ov = *(const short8*)&pl[ww][q][d0];
#pragma unroll
      for (int j = 0; j < 8; ++j) o[j] += sc * bf2f((u16)ov[j]);
    }
    float invL = 1.f / L;
    short8 ob;
#pragma unroll
    for (int j = 0; j < 8; ++j) ob[j] = (short)f2bf(o[j] * invL);
    *(short8*)&yb[(size_t)(b * 2048 + q0 + q) * 1024 + h * 64 + d0] = ob;
  }
}

extern "C" void kernel_launch(void* const* d_in, const int* in_sizes, int n_in,
                              void* d_out, int out_size, void* d_ws, size_t ws_size,
                              hipStream_t stream) {
  const float* x = (const float*)d_in[0];    // [4096][1024]
  const float* Wa = (const float*)d_in[1];   // [1024][3072]
  const float* Wp = (const float*)d_in[2];   // [1024][1024]
  char* ws = (char*)d_ws;
  u16* xb   = (u16*)(ws);              // [4096][1024] bf16
  u16* Wat  = (u16*)(ws + 8388608);    // [3072][1024] bf16 (W_attn^T, Q rows pre-scaled)
  u16* Wpt  = (u16*)(ws + 14680064);   // [1024][1024] bf16 (W_proj^T)
  u16* qkvb = (u16*)(ws + 16777216);   // [4096][3072] bf16
  u16* Vt   = (u16*)(ws + 41943040);   // [32][64][2048] bf16
  u16* yb   = (u16*)(ws + 50331648);   // [4096][1024] bf16

  const float CS = 0.03125f * 1.44269504088896f;  // rsqrt(1024) * log2(e)
  prep_kernel<<<5120, 256, 0, stream>>>(x, xb, Wa, Wat, Wp, Wpt, CS);
  gemm_kernel<1><<<dim3(24, 32), 256, 0, stream>>>(xb, Wat, (void*)qkvb, 3072, 1024);
  transV_kernel<<<dim3(64, 32), 256, 0, stream>>>(qkvb, Vt);
  attn_kernel<<<2048, 256, 0, stream>>>(qkvb, Vt, yb);
  gemm_kernel<0><<<dim3(8, 32), 256, 0, stream>>>(yb, Wpt, d_out, 1024, 1024);
}